// Round 8
// baseline (1423.693 us; speedup 1.0000x reference)
//
#include <hip/hip_runtime.h>

// CfC actor-critic forward: B=256, T=1024, OBS=32, H=128, A=8.
// R8: 4 waves/block (was 8), each wave owns TWO 16-col output tiles for
// backbone+gates -> halves redundant LDS A-frag reads, doubles MFMA ILP per
// wave, less barrier skew. Weights in registers (~136 VGPRs of B-frags), so
// amdgpu_waves_per_eu(1,2) and NO launch_bounds (needs >128 VGPR budget).
// R7 lesson: exp2f() is a libm call; use __builtin_amdgcn_exp2f (v_exp_f32).

typedef _Float16 half8 __attribute__((ext_vector_type(8)));
typedef float f32x4 __attribute__((ext_vector_type(4)));

#define T_STEPS 1024
#define OBS 32
#define H 128
#define A_DIM 8
#define NW 4
#define NT (NW * 64)
#define ROWS 4
#define NBLK 64

#define ZIN_P 168   // [16][168] f16: cols 0-31 x, 32-159 h
#define ZF_P 136    // [16][136] f16: z

__device__ __forceinline__ float fexp2(float x) { return __builtin_amdgcn_exp2f(x); }
__device__ __forceinline__ float frcp(float x) { return __builtin_amdgcn_rcpf(x); }

__attribute__((amdgpu_flat_work_group_size(NT, NT), amdgpu_waves_per_eu(1, 2)))
__global__ void cfc_kernel(
    const float* __restrict__ obs,
    const float* __restrict__ Wb,  const float* __restrict__ bb,
    const float* __restrict__ Wff1, const float* __restrict__ bff1,
    const float* __restrict__ Wff2, const float* __restrict__ bff2,
    const float* __restrict__ Wta, const float* __restrict__ bta,
    const float* __restrict__ Wtb, const float* __restrict__ btb,
    const float* __restrict__ Wa,  const float* __restrict__ ba,
    const float* __restrict__ Wc,  const float* __restrict__ bc,
    float* __restrict__ out_mean, float* __restrict__ out_value)
{
    const int b0 = blockIdx.x * ROWS;
    const int tid = threadIdx.x;
    const int w = tid >> 6, l = tid & 63;
    const int lo = l & 15, hi = l >> 4;      // lo: M/N index, hi: k-group

    __shared__ _Float16 zin[16][ZIN_P];      // [x_t | h_{t-1}]
    __shared__ _Float16 zf[16][ZF_P];        // z(t)

    // ---------------- preload B-fragments: wave w owns cols 32w..32w+31 ----
    half8 Bb[2][5];
    half8 Bg0[2][4], Bg1[2][4], Bg2[2][4];
    float bbv[2], bg1v[2], bg2v[2], bg3v[2];
#pragma unroll
    for (int u = 0; u < 2; ++u) {
        const int colB = w * 32 + u * 16 + lo;
#pragma unroll
        for (int ks = 0; ks < 5; ++ks)
#pragma unroll
            for (int j = 0; j < 8; ++j) {
                int k = ks * 32 + hi * 8 + j;
                Bb[u][ks][j] = (_Float16)Wb[k * H + colB];
            }
        bbv[u] = bb[colB];
#pragma unroll
        for (int ks = 0; ks < 4; ++ks)
#pragma unroll
            for (int j = 0; j < 8; ++j) {
                int k = ks * 32 + hi * 8 + j;
                Bg0[u][ks][j] = (_Float16)Wff1[k * H + colB];
                Bg1[u][ks][j] = (_Float16)Wff2[k * H + colB];
                Bg2[u][ks][j] = (_Float16)(Wta[k * H + colB] + Wtb[k * H + colB]);
            }
        bg1v[u] = bff1[colB];
        bg2v[u] = bff2[colB];
        bg3v[u] = bta[colB] + btb[colB];
    }

    half8 Bh[4];                              // heads Hx9 on wave 1
    float bh = 0.f;
    if (w == 1) {
#pragma unroll
        for (int ks = 0; ks < 4; ++ks)
#pragma unroll
            for (int j = 0; j < 8; ++j) {
                int k = ks * 32 + hi * 8 + j;
                float v = (lo < 8) ? Wa[k * A_DIM + lo] : ((lo == 8) ? Wc[k] : 0.0f);
                Bh[ks][j] = (_Float16)v;
            }
        bh = (lo < 8) ? ba[lo] : ((lo == 8) ? bc[0] : 0.0f);
    }

    // ---------------- init LDS ----------------
    for (int i = tid; i < 16 * ZIN_P; i += NT) (&zin[0][0])[i] = (_Float16)0.0f;
    __syncthreads();
    const int rX = l >> 5, cX = l & 31;       // wave 0: rows {rX, rX+2}
    if (w == 0) {
        zin[rX][cX]     = (_Float16)obs[((size_t)(b0 + rX) * T_STEPS) * OBS + cX];
        zin[rX + 2][cX] = (_Float16)obs[((size_t)(b0 + rX + 2) * T_STEPS) * OBS + cX];
    }
    __syncthreads();

    // obs prefetch ring, 2 steps deep (wave 0)
    float oxA0 = 0.f, oxA1 = 0.f, oxB0 = 0.f, oxB1 = 0.f;
    if (w == 0) {
        oxA0 = obs[((size_t)(b0 + rX) * T_STEPS + 1) * OBS + cX];
        oxA1 = obs[((size_t)(b0 + rX + 2) * T_STEPS + 1) * OBS + cX];
        oxB0 = obs[((size_t)(b0 + rX) * T_STEPS + 2) * OBS + cX];
        oxB1 = obs[((size_t)(b0 + rX + 2) * T_STEPS + 2) * OBS + cX];
    }

    // ================= main loop: 2 barriers/step =================
    for (int t = 0; t < T_STEPS; ++t) {
        // ---- phase 1: z = lecun_tanh([x|h] @ Wb + bb) ----
        half8 A0 = *(const half8*)&zin[lo][0 * 32 + hi * 8];
        half8 A1 = *(const half8*)&zin[lo][1 * 32 + hi * 8];
        half8 A2 = *(const half8*)&zin[lo][2 * 32 + hi * 8];
        half8 A3 = *(const half8*)&zin[lo][3 * 32 + hi * 8];
        half8 A4 = *(const half8*)&zin[lo][4 * 32 + hi * 8];
        f32x4 az[2];
#pragma unroll
        for (int u = 0; u < 2; ++u) {
            f32x4 a = {bbv[u], bbv[u], bbv[u], bbv[u]};
            a = __builtin_amdgcn_mfma_f32_16x16x32_f16(A0, Bb[u][0], a, 0, 0, 0);
            a = __builtin_amdgcn_mfma_f32_16x16x32_f16(A1, Bb[u][1], a, 0, 0, 0);
            a = __builtin_amdgcn_mfma_f32_16x16x32_f16(A2, Bb[u][2], a, 0, 0, 0);
            a = __builtin_amdgcn_mfma_f32_16x16x32_f16(A3, Bb[u][3], a, 0, 0, 0);
            a = __builtin_amdgcn_mfma_f32_16x16x32_f16(A4, Bb[u][4], a, 0, 0, 0);
            az[u] = a;
        }

        // heads on h_{t-1} (wave 1; A1..A4 are the h k-subtiles)
        if (w == 1 && t > 0) {
            f32x4 acch = {bh, bh, bh, bh};
            acch = __builtin_amdgcn_mfma_f32_16x16x32_f16(A1, Bh[0], acch, 0, 0, 0);
            acch = __builtin_amdgcn_mfma_f32_16x16x32_f16(A2, Bh[1], acch, 0, 0, 0);
            acch = __builtin_amdgcn_mfma_f32_16x16x32_f16(A3, Bh[2], acch, 0, 0, 0);
            acch = __builtin_amdgcn_mfma_f32_16x16x32_f16(A4, Bh[3], acch, 0, 0, 0);
            if (hi == 0 && lo < 9) {
#pragma unroll
                for (int j = 0; j < 4; ++j) {
                    if (lo < 8) out_mean[((size_t)(b0 + j) * T_STEPS + (t - 1)) * A_DIM + lo] = acch[j];
                    else        out_value[(size_t)(b0 + j) * T_STEPS + (t - 1)] = acch[j];
                }
            }
        }

        // z-act -> zf: 1.7159*tanh(0.666x) = 1.7159 - 3.4318/(2^(1.9216697x)+1)
#pragma unroll
        for (int u = 0; u < 2; ++u)
#pragma unroll
            for (int j = 0; j < 4; ++j) {
                float r = frcp(fexp2(1.9216697f * az[u][j]) + 1.0f);
                zf[hi * 4 + j][w * 32 + u * 16 + lo] = (_Float16)fmaf(-3.4318f, r, 1.7159f);
            }
        __syncthreads();

        // ---- phase 2: gates + combine -> h(t) ----
        half8 Z0 = *(const half8*)&zf[lo][0 * 32 + hi * 8];
        half8 Z1 = *(const half8*)&zf[lo][1 * 32 + hi * 8];
        half8 Z2 = *(const half8*)&zf[lo][2 * 32 + hi * 8];
        half8 Z3 = *(const half8*)&zf[lo][3 * 32 + hi * 8];
#pragma unroll
        for (int u = 0; u < 2; ++u) {
            f32x4 a1 = {bg1v[u], bg1v[u], bg1v[u], bg1v[u]};
            f32x4 a2 = {bg2v[u], bg2v[u], bg2v[u], bg2v[u]};
            f32x4 a3 = {bg3v[u], bg3v[u], bg3v[u], bg3v[u]};
            a1 = __builtin_amdgcn_mfma_f32_16x16x32_f16(Z0, Bg0[u][0], a1, 0, 0, 0);
            a2 = __builtin_amdgcn_mfma_f32_16x16x32_f16(Z0, Bg1[u][0], a2, 0, 0, 0);
            a3 = __builtin_amdgcn_mfma_f32_16x16x32_f16(Z0, Bg2[u][0], a3, 0, 0, 0);
            a1 = __builtin_amdgcn_mfma_f32_16x16x32_f16(Z1, Bg0[u][1], a1, 0, 0, 0);
            a2 = __builtin_amdgcn_mfma_f32_16x16x32_f16(Z1, Bg1[u][1], a2, 0, 0, 0);
            a3 = __builtin_amdgcn_mfma_f32_16x16x32_f16(Z1, Bg2[u][1], a3, 0, 0, 0);
            a1 = __builtin_amdgcn_mfma_f32_16x16x32_f16(Z2, Bg0[u][2], a1, 0, 0, 0);
            a2 = __builtin_amdgcn_mfma_f32_16x16x32_f16(Z2, Bg1[u][2], a2, 0, 0, 0);
            a3 = __builtin_amdgcn_mfma_f32_16x16x32_f16(Z2, Bg2[u][2], a3, 0, 0, 0);
            a1 = __builtin_amdgcn_mfma_f32_16x16x32_f16(Z3, Bg0[u][3], a1, 0, 0, 0);
            a2 = __builtin_amdgcn_mfma_f32_16x16x32_f16(Z3, Bg1[u][3], a2, 0, 0, 0);
            a3 = __builtin_amdgcn_mfma_f32_16x16x32_f16(Z3, Bg2[u][3], a3, 0, 0, 0);
#pragma unroll
            for (int j = 0; j < 4; ++j) {
                float r1 = frcp(fexp2(2.8853901f * a1[j]) + 1.0f);
                float ff1 = fmaf(-2.0f, r1, 1.0f);
                float r2 = frcp(fexp2(2.8853901f * a2[j]) + 1.0f);
                float ff2 = fmaf(-2.0f, r2, 1.0f);
                float ti = frcp(1.0f + fexp2(-1.44269504f * a3[j]));
                zin[hi * 4 + j][32 + w * 32 + u * 16 + lo] = (_Float16)(ff1 + ti * (ff2 - ff1));
            }
        }

        // x(t+1) -> zin (wave 0), refill 2-deep ring
        if (w == 0 && t + 1 < T_STEPS) {
            zin[rX][cX]     = (_Float16)oxA0;
            zin[rX + 2][cX] = (_Float16)oxA1;
            oxA0 = oxB0; oxA1 = oxB1;
            const int tf = t + 3;
            if (tf < T_STEPS) {
                oxB0 = obs[((size_t)(b0 + rX) * T_STEPS + tf) * OBS + cX];
                oxB1 = obs[((size_t)(b0 + rX + 2) * T_STEPS + tf) * OBS + cX];
            }
        }
        __syncthreads();
    }

    // ---- epilogue: heads for s = T-1 ----
    if (w == 1) {
        half8 A1 = *(const half8*)&zin[lo][32 + 0 * 32 + hi * 8];
        half8 A2 = *(const half8*)&zin[lo][32 + 1 * 32 + hi * 8];
        half8 A3 = *(const half8*)&zin[lo][32 + 2 * 32 + hi * 8];
        half8 A4 = *(const half8*)&zin[lo][32 + 3 * 32 + hi * 8];
        f32x4 acch = {bh, bh, bh, bh};
        acch = __builtin_amdgcn_mfma_f32_16x16x32_f16(A1, Bh[0], acch, 0, 0, 0);
        acch = __builtin_amdgcn_mfma_f32_16x16x32_f16(A2, Bh[1], acch, 0, 0, 0);
        acch = __builtin_amdgcn_mfma_f32_16x16x32_f16(A3, Bh[2], acch, 0, 0, 0);
        acch = __builtin_amdgcn_mfma_f32_16x16x32_f16(A4, Bh[3], acch, 0, 0, 0);
        if (hi == 0 && lo < 9) {
#pragma unroll
            for (int j = 0; j < 4; ++j) {
                if (lo < 8) out_mean[((size_t)(b0 + j) * T_STEPS + (T_STEPS - 1)) * A_DIM + lo] = acch[j];
                else        out_value[(size_t)(b0 + j) * T_STEPS + (T_STEPS - 1)] = acch[j];
            }
        }
    }
}

extern "C" void kernel_launch(void* const* d_in, const int* in_sizes, int n_in,
                              void* d_out, int out_size, void* d_ws, size_t ws_size,
                              hipStream_t stream) {
    (void)in_sizes; (void)n_in; (void)d_ws; (void)ws_size; (void)out_size;
    const float* obs  = (const float*)d_in[0];
    const float* Wb   = (const float*)d_in[1];
    const float* bb   = (const float*)d_in[2];
    const float* Wff1 = (const float*)d_in[3];
    const float* bff1 = (const float*)d_in[4];
    const float* Wff2 = (const float*)d_in[5];
    const float* bff2 = (const float*)d_in[6];
    const float* Wta  = (const float*)d_in[7];
    const float* bta  = (const float*)d_in[8];
    const float* Wtb  = (const float*)d_in[9];
    const float* btb  = (const float*)d_in[10];
    const float* Wa   = (const float*)d_in[11];
    const float* ba   = (const float*)d_in[12];
    const float* Wc   = (const float*)d_in[13];
    const float* bc   = (const float*)d_in[14];
    float* out = (float*)d_out;
    float* out_mean  = out;
    float* out_value = out + (size_t)256 * 1024 * 8;

    cfc_kernel<<<dim3(NBLK), dim3(NT), 0, stream>>>(
        obs, Wb, bb, Wff1, bff1, Wff2, bff2, Wta, bta, Wtb, btb,
        Wa, ba, Wc, bc, out_mean, out_value);
}

// Round 9
// 1137.105 us; speedup vs baseline: 1.2520x; 1.2520x over previous
//
#include <hip/hip_runtime.h>

// CfC actor-critic forward: B=256, T=1024, OBS=32, H=128, A=8.
// R9 = R6 (best: 8 waves, ROWS=4, 64 blocks, weights-in-regs MFMA) plus:
//  - LDS pitches ZIN_P=164 / ZF_P=132: row strides 82/66 words (mod 32 = 18/2)
//    -> A-frag b128 reads and h/z b16 writes <=2-way bank aliasing (free).
//  - biases folded into MFMA C-init.
//  - activations via __builtin_amdgcn_exp2f (bare v_exp_f32; R7's exp2f was
//    a libm call and regressed).
//  - phase-1 MFMA chain split into two accumulators.
//  - obs prefetch ring 2 deep on waves 0-1.

typedef _Float16 half8 __attribute__((ext_vector_type(8)));
typedef float f32x4 __attribute__((ext_vector_type(4)));

#define T_STEPS 1024
#define OBS 32
#define H 128
#define A_DIM 8
#define NW 8
#define NT (NW * 64)
#define ROWS 4
#define NBLK 64

#define ZIN_P 164   // [16][164] f16: cols 0-31 x, 32-159 h; stride 82 words
#define ZF_P 132    // [16][132] f16: z; stride 66 words

__device__ __forceinline__ float fexp2(float x) { return __builtin_amdgcn_exp2f(x); }
__device__ __forceinline__ float frcp(float x) { return __builtin_amdgcn_rcpf(x); }

__global__ void __launch_bounds__(NT) cfc_kernel(
    const float* __restrict__ obs,
    const float* __restrict__ Wb,  const float* __restrict__ bb,
    const float* __restrict__ Wff1, const float* __restrict__ bff1,
    const float* __restrict__ Wff2, const float* __restrict__ bff2,
    const float* __restrict__ Wta, const float* __restrict__ bta,
    const float* __restrict__ Wtb, const float* __restrict__ btb,
    const float* __restrict__ Wa,  const float* __restrict__ ba,
    const float* __restrict__ Wc,  const float* __restrict__ bc,
    float* __restrict__ out_mean, float* __restrict__ out_value)
{
    const int b0 = blockIdx.x * ROWS;
    const int tid = threadIdx.x;
    const int w = tid >> 6, l = tid & 63;
    const int lo = l & 15, hi = l >> 4;      // lo: M/N index, hi: k-group

    __shared__ _Float16 zin[16][ZIN_P];      // [x_t | h_{t-1}]
    __shared__ _Float16 zf[16][ZF_P];        // z(t)

    // ---------------- preload B-fragments (f16) ----------------
    const int colB = w * 16 + lo;

    half8 Bb[5];                              // backbone 160xH
#pragma unroll
    for (int ks = 0; ks < 5; ++ks)
#pragma unroll
        for (int j = 0; j < 8; ++j) {
            int k = ks * 32 + hi * 8 + j;
            Bb[ks][j] = (_Float16)Wb[k * H + colB];
        }
    const float bbv = bb[colB];

    half8 Bg0[4], Bg1[4], Bg2[4];             // gates HxH
#pragma unroll
    for (int ks = 0; ks < 4; ++ks)
#pragma unroll
        for (int j = 0; j < 8; ++j) {
            int k = ks * 32 + hi * 8 + j;
            Bg0[ks][j] = (_Float16)Wff1[k * H + colB];
            Bg1[ks][j] = (_Float16)Wff2[k * H + colB];
            Bg2[ks][j] = (_Float16)(Wta[k * H + colB] + Wtb[k * H + colB]);
        }
    const float bg1 = bff1[colB], bg2 = bff2[colB], bg3 = bta[colB] + btb[colB];

    half8 Bh[4];                              // heads Hx9 (wave 7)
    float bh = 0.f;
    if (w == 7) {
#pragma unroll
        for (int ks = 0; ks < 4; ++ks)
#pragma unroll
            for (int j = 0; j < 8; ++j) {
                int k = ks * 32 + hi * 8 + j;
                float v = (lo < 8) ? Wa[k * A_DIM + lo] : ((lo == 8) ? Wc[k] : 0.0f);
                Bh[ks][j] = (_Float16)v;
            }
        bh = (lo < 8) ? ba[lo] : ((lo == 8) ? bc[0] : 0.0f);
    }

    // ---------------- init LDS ----------------
    for (int i = tid; i < 16 * ZIN_P; i += NT) (&zin[0][0])[i] = (_Float16)0.0f;
    __syncthreads();
    const int rX = (w << 1) | (l >> 5), cX = l & 31;   // waves 0-1: rows 0-3
    if (w < 2) zin[rX][cX] = (_Float16)obs[((size_t)(b0 + rX) * T_STEPS) * OBS + cX];
    __syncthreads();

    // obs prefetch ring, 2 steps deep (waves 0-1)
    float oxA = 0.f, oxB = 0.f;
    if (w < 2) {
        oxA = obs[((size_t)(b0 + rX) * T_STEPS + 1) * OBS + cX];
        oxB = obs[((size_t)(b0 + rX) * T_STEPS + 2) * OBS + cX];
    }

    // ================= main loop: 2 barriers/step =================
    for (int t = 0; t < T_STEPS; ++t) {
        // ---- phase 1: z = lecun_tanh([x|h] @ Wb + bb) ----
        half8 A0 = *(const half8*)&zin[lo][0 * 32 + hi * 8];
        half8 A1 = *(const half8*)&zin[lo][1 * 32 + hi * 8];
        half8 A2 = *(const half8*)&zin[lo][2 * 32 + hi * 8];
        half8 A3 = *(const half8*)&zin[lo][3 * 32 + hi * 8];
        half8 A4 = *(const half8*)&zin[lo][4 * 32 + hi * 8];
        f32x4 az0 = {bbv, bbv, bbv, bbv};
        f32x4 az1 = {0.f, 0.f, 0.f, 0.f};
        az0 = __builtin_amdgcn_mfma_f32_16x16x32_f16(A0, Bb[0], az0, 0, 0, 0);
        az1 = __builtin_amdgcn_mfma_f32_16x16x32_f16(A1, Bb[1], az1, 0, 0, 0);
        az0 = __builtin_amdgcn_mfma_f32_16x16x32_f16(A2, Bb[2], az0, 0, 0, 0);
        az1 = __builtin_amdgcn_mfma_f32_16x16x32_f16(A3, Bb[3], az1, 0, 0, 0);
        az0 = __builtin_amdgcn_mfma_f32_16x16x32_f16(A4, Bb[4], az0, 0, 0, 0);

        // heads on h_{t-1} (wave 7; A1..A4 are the h k-subtiles)
        if (w == 7 && t > 0) {
            f32x4 acch = {bh, bh, bh, bh};
            acch = __builtin_amdgcn_mfma_f32_16x16x32_f16(A1, Bh[0], acch, 0, 0, 0);
            acch = __builtin_amdgcn_mfma_f32_16x16x32_f16(A2, Bh[1], acch, 0, 0, 0);
            acch = __builtin_amdgcn_mfma_f32_16x16x32_f16(A3, Bh[2], acch, 0, 0, 0);
            acch = __builtin_amdgcn_mfma_f32_16x16x32_f16(A4, Bh[3], acch, 0, 0, 0);
            if (hi == 0 && lo < 9) {
#pragma unroll
                for (int j = 0; j < 4; ++j) {
                    if (lo < 8) out_mean[((size_t)(b0 + j) * T_STEPS + (t - 1)) * A_DIM + lo] = acch[j];
                    else        out_value[(size_t)(b0 + j) * T_STEPS + (t - 1)] = acch[j];
                }
            }
        }

        // z-act -> zf: 1.7159*tanh(0.666x) = 1.7159 - 3.4318/(2^(1.9216697x)+1)
#pragma unroll
        for (int j = 0; j < 4; ++j) {
            float s = az0[j] + az1[j];
            float r = frcp(fexp2(1.9216697f * s) + 1.0f);
            zf[hi * 4 + j][colB] = (_Float16)fmaf(-3.4318f, r, 1.7159f);
        }
        __syncthreads();

        // ---- phase 2: gates + combine -> h(t) ----
        half8 Z0 = *(const half8*)&zf[lo][0 * 32 + hi * 8];
        half8 Z1 = *(const half8*)&zf[lo][1 * 32 + hi * 8];
        half8 Z2 = *(const half8*)&zf[lo][2 * 32 + hi * 8];
        half8 Z3 = *(const half8*)&zf[lo][3 * 32 + hi * 8];
        f32x4 a1 = {bg1, bg1, bg1, bg1};
        f32x4 a2 = {bg2, bg2, bg2, bg2};
        f32x4 a3 = {bg3, bg3, bg3, bg3};
        a1 = __builtin_amdgcn_mfma_f32_16x16x32_f16(Z0, Bg0[0], a1, 0, 0, 0);
        a2 = __builtin_amdgcn_mfma_f32_16x16x32_f16(Z0, Bg1[0], a2, 0, 0, 0);
        a3 = __builtin_amdgcn_mfma_f32_16x16x32_f16(Z0, Bg2[0], a3, 0, 0, 0);
        a1 = __builtin_amdgcn_mfma_f32_16x16x32_f16(Z1, Bg0[1], a1, 0, 0, 0);
        a2 = __builtin_amdgcn_mfma_f32_16x16x32_f16(Z1, Bg1[1], a2, 0, 0, 0);
        a3 = __builtin_amdgcn_mfma_f32_16x16x32_f16(Z1, Bg2[1], a3, 0, 0, 0);
        a1 = __builtin_amdgcn_mfma_f32_16x16x32_f16(Z2, Bg0[2], a1, 0, 0, 0);
        a2 = __builtin_amdgcn_mfma_f32_16x16x32_f16(Z2, Bg1[2], a2, 0, 0, 0);
        a3 = __builtin_amdgcn_mfma_f32_16x16x32_f16(Z2, Bg2[2], a3, 0, 0, 0);
        a1 = __builtin_amdgcn_mfma_f32_16x16x32_f16(Z3, Bg0[3], a1, 0, 0, 0);
        a2 = __builtin_amdgcn_mfma_f32_16x16x32_f16(Z3, Bg1[3], a2, 0, 0, 0);
        a3 = __builtin_amdgcn_mfma_f32_16x16x32_f16(Z3, Bg2[3], a3, 0, 0, 0);

#pragma unroll
        for (int j = 0; j < 4; ++j) {
            float r1 = frcp(fexp2(2.8853901f * a1[j]) + 1.0f);
            float ff1 = fmaf(-2.0f, r1, 1.0f);
            float r2 = frcp(fexp2(2.8853901f * a2[j]) + 1.0f);
            float ff2 = fmaf(-2.0f, r2, 1.0f);
            float ti = frcp(1.0f + fexp2(-1.44269504f * a3[j]));
            zin[hi * 4 + j][32 + colB] = (_Float16)(ff1 + ti * (ff2 - ff1));
        }

        // x(t+1) -> zin (waves 0-1), refill 2-deep ring
        if (w < 2 && t + 1 < T_STEPS) {
            zin[rX][cX] = (_Float16)oxA;
            oxA = oxB;
            const int tf = t + 3;
            oxB = (tf < T_STEPS) ? obs[((size_t)(b0 + rX) * T_STEPS + tf) * OBS + cX] : 0.0f;
        }
        __syncthreads();
    }

    // ---- epilogue: heads for s = T-1 ----
    if (w == 7) {
        half8 A1 = *(const half8*)&zin[lo][32 + 0 * 32 + hi * 8];
        half8 A2 = *(const half8*)&zin[lo][32 + 1 * 32 + hi * 8];
        half8 A3 = *(const half8*)&zin[lo][32 + 2 * 32 + hi * 8];
        half8 A4 = *(const half8*)&zin[lo][32 + 3 * 32 + hi * 8];
        f32x4 acch = {bh, bh, bh, bh};
        acch = __builtin_amdgcn_mfma_f32_16x16x32_f16(A1, Bh[0], acch, 0, 0, 0);
        acch = __builtin_amdgcn_mfma_f32_16x16x32_f16(A2, Bh[1], acch, 0, 0, 0);
        acch = __builtin_amdgcn_mfma_f32_16x16x32_f16(A3, Bh[2], acch, 0, 0, 0);
        acch = __builtin_amdgcn_mfma_f32_16x16x32_f16(A4, Bh[3], acch, 0, 0, 0);
        if (hi == 0 && lo < 9) {
#pragma unroll
            for (int j = 0; j < 4; ++j) {
                if (lo < 8) out_mean[((size_t)(b0 + j) * T_STEPS + (T_STEPS - 1)) * A_DIM + lo] = acch[j];
                else        out_value[(size_t)(b0 + j) * T_STEPS + (T_STEPS - 1)] = acch[j];
            }
        }
    }
}

extern "C" void kernel_launch(void* const* d_in, const int* in_sizes, int n_in,
                              void* d_out, int out_size, void* d_ws, size_t ws_size,
                              hipStream_t stream) {
    (void)in_sizes; (void)n_in; (void)d_ws; (void)ws_size; (void)out_size;
    const float* obs  = (const float*)d_in[0];
    const float* Wb   = (const float*)d_in[1];
    const float* bb   = (const float*)d_in[2];
    const float* Wff1 = (const float*)d_in[3];
    const float* bff1 = (const float*)d_in[4];
    const float* Wff2 = (const float*)d_in[5];
    const float* bff2 = (const float*)d_in[6];
    const float* Wta  = (const float*)d_in[7];
    const float* bta  = (const float*)d_in[8];
    const float* Wtb  = (const float*)d_in[9];
    const float* btb  = (const float*)d_in[10];
    const float* Wa   = (const float*)d_in[11];
    const float* ba   = (const float*)d_in[12];
    const float* Wc   = (const float*)d_in[13];
    const float* bc   = (const float*)d_in[14];
    float* out = (float*)d_out;
    float* out_mean  = out;
    float* out_value = out + (size_t)256 * 1024 * 8;

    cfc_kernel<<<dim3(NBLK), dim3(NT), 0, stream>>>(
        obs, Wb, bb, Wff1, bff1, Wff2, bff2, Wta, bta, Wtb, btb,
        Wa, ba, Wc, bc, out_mean, out_value);
}